// Round 6
// baseline (397.953 us; speedup 1.0000x reference)
//
#include <hip/hip_runtime.h>
#include <float.h>
#include <math.h>

#define TOKENS 16384
#define HIDDEN 2048
#define NEXP 128
#define TOPK 8
#define NCAND 12
#define DELTA 5e-4f

#define BM 32
#define KIT2 (HIDDEN / 32)   // 64 iterations of BK=32 (2 k16-steps each)

typedef float f32x16 __attribute__((ext_vector_type(16)));
typedef short bf16x8 __attribute__((ext_vector_type(8)));

__device__ __forceinline__ unsigned pack_hi(float a, float b) {
    return (__float_as_uint(a) >> 16) | (__float_as_uint(b) & 0xFFFF0000u);
}
__device__ __forceinline__ float resid(float a) {
    return a - __uint_as_float(__float_as_uint(a) & 0xFFFF0000u);
}

__device__ __forceinline__ bf16x8 pack8_hi(const float4 a, const float4 b) {
    union { uint4 u; bf16x8 v; } t;
    t.u.x = pack_hi(a.x, a.y); t.u.y = pack_hi(a.z, a.w);
    t.u.z = pack_hi(b.x, b.y); t.u.w = pack_hi(b.z, b.w);
    return t.v;
}
__device__ __forceinline__ bf16x8 pack8_lo(const float4 a, const float4 b) {
    union { uint4 u; bf16x8 v; } t;
    t.u.x = pack_hi(resid(a.x), resid(a.y)); t.u.y = pack_hi(resid(a.z), resid(a.w));
    t.u.z = pack_hi(resid(b.x), resid(b.y)); t.u.w = pack_hi(resid(b.z), resid(b.w));
    return t.v;
}

// ---------------------------------------------------------------------------
// K0: pre-split W into 32x32x16-fragment-ordered bf16 hi/lo (verified r6).
// Chunk c = k16*8 + nt*2 + hl; lane l: expert = nt*32+(l&31), k = k16*16+(l>>5)*8+j.
// UNCHANGED.
// ---------------------------------------------------------------------------
__global__ __launch_bounds__(256) void presplit_w(const float* __restrict__ W,
                                                  unsigned short* __restrict__ Ws) {
    const int c = blockIdx.x * 256 + threadIdx.x;   // [0, 65536)
    const int lane = c & 63;
    const int q = c >> 6;
    const int hl = q & 1;
    const int nt = (q >> 1) & 3;
    const int k16 = q >> 3;
    const int e = nt * 32 + (lane & 31);
    const int k0 = k16 * 16 + (lane >> 5) * 8;
    const float* wp = W + (size_t)e * HIDDEN + k0;
    float4 a = *(const float4*)wp;
    float4 b = *(const float4*)(wp + 4);
    if (hl) {
        a.x = resid(a.x); a.y = resid(a.y); a.z = resid(a.z); a.w = resid(a.w);
        b.x = resid(b.x); b.y = resid(b.y); b.z = resid(b.z); b.w = resid(b.w);
    }
    uint4 o;
    o.x = pack_hi(a.x, a.y); o.y = pack_hi(a.z, a.w);
    o.z = pack_hi(b.x, b.y); o.w = pack_hi(b.z, b.w);
    *(uint4*)(Ws + (size_t)c * 8) = o;
}

// ---------------------------------------------------------------------------
// K1 (v6): ZERO-LDS, ZERO-BARRIER all-register GEMM.
//  Round-1's retry with the failure cause fixed: launch_bounds(256,4) caps
//  VGPR at 128 (round 1's plain (256) let the compiler target 8 waves/EU =
//  48 VGPR and sink the whole register pipeline). BK=32: per iter 2 k16
//  steps = 6 MFMA; A = 4 per-lane float4 loads (lane l -> row l&31, k-half
//  (l>>5)*8 — divergent across rows but 16 B/lane), B = 4 lane-linear
//  float4 loads from fragment-ordered Ws (L2-hot). Period-2 pipeline with
//  individually NAMED stage registers (all indices static, rule #20);
//  issue-to-use distance = one compute phase, stalls decorrelated across
//  16 independent waves/CU (4/EU). No inter-wave coupling of any kind:
//  compiler's own waitcnt insertion is exact (no LDS aliasing to poison).
//  Accumulation order over (g asc, hh/hl/lh) identical -> bit-identical
//  logits vs rounds 0/2/3/5 (absmax 0.015625).
// ---------------------------------------------------------------------------
__global__ __launch_bounds__(256, 4) void router_gemm(const float* __restrict__ X,
                                                      const unsigned short* __restrict__ Ws,
                                                      float* __restrict__ logits) {
    const int tid = threadIdx.x;
    const int lane = tid & 63;
    const int wid = tid >> 6;          // 0..3 = expert group
    const int t0 = blockIdx.x * BM;

    // A: lane l owns row t0+(l&31), k-offset (l>>5)*8 within each k16 step.
    const float* xp = X + (size_t)(t0 + (lane & 31)) * HIDDEN + (lane >> 5) * 8;
    // B: chunk (g*8 + wid*2 + hl), 16 B/lane lane-linear.
    const unsigned short* bp = Ws + (size_t)(wid * 2) * 512 + (size_t)lane * 8;

    f32x16 acc;
#pragma unroll
    for (int r = 0; r < 16; ++r) acc[r] = 0.f;

    // ---- named pipeline stages (2 iters deep, all statically indexed) ----
    float4 S0_f0a, S0_f0b, S0_f1a, S0_f1b;   // A: k16 steps g=2kt, 2kt+1
    bf16x8 S0_bh0, S0_bl0, S0_bh1, S0_bl1;   // B: same steps, hi/lo
    float4 S1_f0a, S1_f0b, S1_f1a, S1_f1b;
    bf16x8 S1_bh0, S1_bl0, S1_bh1, S1_bl1;

#define LOADS(S, kt_)                                                            \
    {                                                                            \
        const int kk = (kt_);                                                    \
        S##_f0a = *(const float4*)(xp + kk * 32);                                \
        S##_f0b = *(const float4*)(xp + kk * 32 + 4);                            \
        S##_f1a = *(const float4*)(xp + kk * 32 + 16);                           \
        S##_f1b = *(const float4*)(xp + kk * 32 + 20);                           \
        S##_bh0 = *(const bf16x8*)(bp + ((size_t)(kk * 2 + 0) * 8 + 0) * 512);   \
        S##_bl0 = *(const bf16x8*)(bp + ((size_t)(kk * 2 + 0) * 8 + 1) * 512);   \
        S##_bh1 = *(const bf16x8*)(bp + ((size_t)(kk * 2 + 1) * 8 + 0) * 512);   \
        S##_bl1 = *(const bf16x8*)(bp + ((size_t)(kk * 2 + 1) * 8 + 1) * 512);   \
    }

#define COMPUTE(S)                                                               \
    {                                                                            \
        const bf16x8 ah0 = pack8_hi(S##_f0a, S##_f0b);                           \
        const bf16x8 al0 = pack8_lo(S##_f0a, S##_f0b);                           \
        acc = __builtin_amdgcn_mfma_f32_32x32x16_bf16(ah0, S##_bh0, acc, 0, 0, 0); \
        acc = __builtin_amdgcn_mfma_f32_32x32x16_bf16(ah0, S##_bl0, acc, 0, 0, 0); \
        acc = __builtin_amdgcn_mfma_f32_32x32x16_bf16(al0, S##_bh0, acc, 0, 0, 0); \
        const bf16x8 ah1 = pack8_hi(S##_f1a, S##_f1b);                           \
        const bf16x8 al1 = pack8_lo(S##_f1a, S##_f1b);                           \
        acc = __builtin_amdgcn_mfma_f32_32x32x16_bf16(ah1, S##_bh1, acc, 0, 0, 0); \
        acc = __builtin_amdgcn_mfma_f32_32x32x16_bf16(ah1, S##_bl1, acc, 0, 0, 0); \
        acc = __builtin_amdgcn_mfma_f32_32x32x16_bf16(al1, S##_bh1, acc, 0, 0, 0); \
    }

    LOADS(S0, 0);
    LOADS(S1, 1);

#pragma unroll 1
    for (int kt = 0; kt < KIT2; kt += 2) {
        COMPUTE(S0);
        {
            int kn = kt + 2; if (kn > KIT2 - 1) kn = KIT2 - 1;   // clamped tail
            LOADS(S0, kn);                                       // (redundant re-load, read-only)
        }
        COMPUTE(S1);
        {
            int kn = kt + 3; if (kn > KIT2 - 1) kn = KIT2 - 1;
            LOADS(S1, kn);
        }
    }

#undef LOADS
#undef COMPUTE

    // C/D: col=lane&31, row=(reg&3)+8*(reg>>2)+4*(lane>>5)  (r6-verified)
    const int e = wid * 32 + (lane & 31);
    const int rbase = 4 * (lane >> 5);
#pragma unroll
    for (int reg = 0; reg < 16; ++reg) {
        const int row = (reg & 3) + 8 * (reg >> 2) + rbase;
        logits[(size_t)(t0 + row) * NEXP + e] = acc[reg];
    }
}

// ---------------------------------------------------------------------------
// K2: fused select+refine. UNCHANGED.
// ---------------------------------------------------------------------------
__global__ __launch_bounds__(256) void router_topk(const float* __restrict__ logits,
                                                   const float* __restrict__ X,
                                                   const float* __restrict__ W,
                                                   float* __restrict__ top_vals,
                                                   float* __restrict__ top_idx) {
    const int lane = threadIdx.x & 63;
    const int t = blockIdx.x * 4 + (threadIdx.x >> 6);
    const float* lrow = logits + (size_t)t * NEXP;
    const float l0 = lrow[lane];
    const float l1 = lrow[lane + 64];
    bool r0 = false, r1 = false;
    float vals[NCAND]; int idxs[NCAND];

#pragma unroll
    for (int it = 0; it < TOPK + 1; ++it) {
        const float c0 = r0 ? -FLT_MAX : l0;
        const float c1 = r1 ? -FLT_MAX : l1;
        float v; int id;
        if (c1 > c0) { v = c1; id = lane + 64; }
        else         { v = c0; id = lane; }
#pragma unroll
        for (int off = 1; off < 64; off <<= 1) {
            const float ov = __shfl_xor(v, off);
            const int   oi = __shfl_xor(id, off);
            if (ov > v || (ov == v && oi < id)) { v = ov; id = oi; }
        }
        vals[it] = v; idxs[it] = id;
        if (id == lane) r0 = true;
        else if (id == lane + 64) r1 = true;
    }

    float ming = FLT_MAX;
#pragma unroll
    for (int i = 0; i < TOPK; ++i) ming = fminf(ming, vals[i] - vals[i + 1]);

    if (ming >= DELTA) {
        if (lane == 0) {
            const float m = vals[0];
            float ex[TOPK], s = 0.f;
#pragma unroll
            for (int i = 0; i < TOPK; ++i) { ex[i] = expf(vals[i] - m); s += ex[i]; }
            const float inv = 1.f / s;
#pragma unroll
            for (int i = 0; i < TOPK; ++i) {
                top_vals[(size_t)t * TOPK + i] = ex[i] * inv;
                top_idx[(size_t)t * TOPK + i] = (float)idxs[i];
            }
        }
        return;
    }

    // ---- slow path (wave-uniform): extend candidates to NCAND
#pragma unroll
    for (int it = TOPK + 1; it < NCAND; ++it) {
        const float c0 = r0 ? -FLT_MAX : l0;
        const float c1 = r1 ? -FLT_MAX : l1;
        float v; int id;
        if (c1 > c0) { v = c1; id = lane + 64; }
        else         { v = c0; id = lane; }
#pragma unroll
        for (int off = 1; off < 64; off <<= 1) {
            const float ov = __shfl_xor(v, off);
            const int   oi = __shfl_xor(id, off);
            if (ov > v || (ov == v && oi < id)) { v = ov; id = oi; }
        }
        vals[it] = v; idxs[it] = id;
        if (id == lane) r0 = true;
        else if (id == lane + 64) r1 = true;
    }

    // exact fp64 recompute of the NCAND candidate logits (coalesced)
    const float* xr = X + (size_t)t * HIDDEN;
    double xd[32];
#pragma unroll
    for (int j = 0; j < 8; ++j) {
        const float4 v = *(const float4*)(xr + j * 256 + lane * 4);
        xd[j * 4 + 0] = (double)v.x; xd[j * 4 + 1] = (double)v.y;
        xd[j * 4 + 2] = (double)v.z; xd[j * 4 + 3] = (double)v.w;
    }
    double acc[NCAND];
#pragma unroll
    for (int c = 0; c < NCAND; ++c) {
        const float* wr = W + (size_t)idxs[c] * HIDDEN;
        double a0 = 0.0, a1 = 0.0;
#pragma unroll
        for (int j = 0; j < 8; ++j) {
            const float4 w = *(const float4*)(wr + j * 256 + lane * 4);
            a0 = fma((double)w.x, xd[j * 4 + 0], a0);
            a1 = fma((double)w.y, xd[j * 4 + 1], a1);
            a0 = fma((double)w.z, xd[j * 4 + 2], a0);
            a1 = fma((double)w.w, xd[j * 4 + 3], a1);
        }
        acc[c] = a0 + a1;
    }
#pragma unroll
    for (int c = 0; c < NCAND; ++c)
#pragma unroll
        for (int off = 1; off < 64; off <<= 1)
            acc[c] += __shfl_xor(acc[c], off);

    int rank[NCAND];
#pragma unroll
    for (int c = 0; c < NCAND; ++c) {
        int r = 0;
#pragma unroll
        for (int m = 0; m < NCAND; ++m)
            if (acc[m] > acc[c] || (acc[m] == acc[c] && idxs[m] < idxs[c])) ++r;
        rank[c] = r;
    }
    double vmax = acc[0];
#pragma unroll
    for (int c = 0; c < NCAND; ++c) if (rank[c] == 0) vmax = acc[c];
    float ex[NCAND], s = 0.f;
#pragma unroll
    for (int c = 0; c < NCAND; ++c) {
        ex[c] = (rank[c] < TOPK) ? expf((float)(acc[c] - vmax)) : 0.f;
        s += ex[c];
    }
    const float inv = 1.f / s;
    if (lane == 0) {
#pragma unroll
        for (int c = 0; c < NCAND; ++c)
            if (rank[c] < TOPK) {
                top_vals[(size_t)t * TOPK + rank[c]] = ex[c] * inv;
                top_idx[(size_t)t * TOPK + rank[c]] = (float)idxs[c];
            }
    }
}

extern "C" void kernel_launch(void* const* d_in, const int* in_sizes, int n_in,
                              void* d_out, int out_size, void* d_ws, size_t ws_size,
                              hipStream_t stream) {
    const float* X = (const float*)d_in[0];   // [16384, 2048] f32
    const float* W = (const float*)d_in[1];   // [128, 2048] f32
    float* logits = (float*)d_out;                          // [16384,128]
    float* tvals  = logits + (size_t)TOKENS * NEXP;         // [16384,8]
    float* tidx   = tvals + (size_t)TOKENS * TOPK;          // [16384,8]

    unsigned short* Wsplit = (unsigned short*)d_ws;         // 1 MB

    presplit_w<<<256, 256, 0, stream>>>(W, Wsplit);
    router_gemm<<<TOKENS / BM, 256, 0, stream>>>(X, Wsplit, logits);
    router_topk<<<TOKENS / 4, 256, 0, stream>>>(logits, X, W, tvals, tidx);
}

// Round 7
// 274.621 us; speedup vs baseline: 1.4491x; 1.4491x over previous
//
#include <hip/hip_runtime.h>
#include <float.h>
#include <math.h>

#define TOKENS 16384
#define HIDDEN 2048
#define NEXP 128
#define TOPK 8
#define NCAND 12
#define DELTA 5e-4f

#define BM 32
#define BK 64
#define KIT (HIDDEN / BK)   // 32 iterations

typedef float f32x16 __attribute__((ext_vector_type(16)));
typedef short bf16x8 __attribute__((ext_vector_type(8)));

__device__ __forceinline__ unsigned pack_hi(float a, float b) {
    return (__float_as_uint(a) >> 16) | (__float_as_uint(b) & 0xFFFF0000u);
}
__device__ __forceinline__ float resid(float a) {
    return a - __uint_as_float(__float_as_uint(a) & 0xFFFF0000u);
}

__device__ __forceinline__ bf16x8 pack8_hi(const float4 a, const float4 b) {
    union { uint4 u; bf16x8 v; } t;
    t.u.x = pack_hi(a.x, a.y); t.u.y = pack_hi(a.z, a.w);
    t.u.z = pack_hi(b.x, b.y); t.u.w = pack_hi(b.z, b.w);
    return t.v;
}
__device__ __forceinline__ bf16x8 pack8_lo(const float4 a, const float4 b) {
    union { uint4 u; bf16x8 v; } t;
    t.u.x = pack_hi(resid(a.x), resid(a.y)); t.u.y = pack_hi(resid(a.z), resid(a.w));
    t.u.z = pack_hi(resid(b.x), resid(b.y)); t.u.w = pack_hi(resid(b.z), resid(b.w));
    return t.v;
}

__device__ __forceinline__ void load_lds_16B(const void* g, void* l) {
    __builtin_amdgcn_global_load_lds(
        (const __attribute__((address_space(1))) unsigned int*)g,
        (__attribute__((address_space(3))) unsigned int*)l, 16, 0, 0);
}

// ---------------------------------------------------------------------------
// K0: pre-split W into 32x32x16-fragment-ordered bf16 hi/lo (verified r6).
// Chunk c = k16*8 + nt*2 + hl; lane l: expert = nt*32+(l&31), k = k16*16+(l>>5)*8+j.
// UNCHANGED.
// ---------------------------------------------------------------------------
__global__ __launch_bounds__(256) void presplit_w(const float* __restrict__ W,
                                                  unsigned short* __restrict__ Ws) {
    const int c = blockIdx.x * 256 + threadIdx.x;   // [0, 65536)
    const int lane = c & 63;
    const int q = c >> 6;
    const int hl = q & 1;
    const int nt = (q >> 1) & 3;
    const int k16 = q >> 3;
    const int e = nt * 32 + (lane & 31);
    const int k0 = k16 * 16 + (lane >> 5) * 8;
    const float* wp = W + (size_t)e * HIDDEN + k0;
    float4 a = *(const float4*)wp;
    float4 b = *(const float4*)(wp + 4);
    if (hl) {
        a.x = resid(a.x); a.y = resid(a.y); a.z = resid(a.z); a.w = resid(a.w);
        b.x = resid(b.x); b.y = resid(b.y); b.z = resid(b.z); b.w = resid(b.w);
    }
    uint4 o;
    o.x = pack_hi(a.x, a.y); o.y = pack_hi(a.z, a.w);
    o.z = pack_hi(b.x, b.y); o.w = pack_hi(b.z, b.w);
    *(uint4*)(Ws + (size_t)c * 8) = o;
}

// ---------------------------------------------------------------------------
// K1 (v7): round-2 v3 GEMM (best measured: ~68 us) VERBATIM, plus fused
// top-k epilogue. After the K-loop, each block's 32x128 logit tile is
// exchanged through LDS (16 KB, overlaying the dead sA region) and each
// wave runs the wave-per-token select+refine for 8 tokens. This removes
// the router_topk dispatch, its launch gap, and the 8 MB logits re-read;
// the top-k work overlaps other blocks' memory phases. Same fp32 bits in
// -> identical top-k results; GEMM numerics bit-identical (absmax 0.015625).
// ---------------------------------------------------------------------------
__global__ __launch_bounds__(256, 2) void router_gemm(const float* __restrict__ X,
                                                      const unsigned short* __restrict__ Ws,
                                                      const float* __restrict__ W,
                                                      float* __restrict__ logits,
                                                      float* __restrict__ top_vals,
                                                      float* __restrict__ top_idx) {
    __shared__ __align__(16) unsigned char smem[81920];
    float (*sA)[BM * BK] = (float (*)[BM * BK])smem;                     // 2 x 8 KB
    unsigned short (*sB)[32 * 512] = (unsigned short (*)[32 * 512])(smem + 16384); // 2 x 32 KB
    float* sLog = (float*)smem;   // 32 x 128 f32 = 16 KB, overlays sA AFTER the loop

    const int tid = threadIdx.x;
    const int lane = tid & 63;
    const int wid = tid >> 6;
    const int t0 = blockIdx.x * BM;

    // A staging: thread -> (arow = tid>>3, aq = tid&7); DMA geometry r2-verified.
    const int ai0 = wid * 2, ai1 = wid * 2 + 1;
    const int ar0 = 4 * ai0 + (lane >> 4);
    const int ar1 = 4 * ai1 + (lane >> 4);
    const int ak0 = ((lane & 15) ^ (ar0 & 15)) * 4;
    const int ak1 = ((lane & 15) ^ (ar1 & 15)) * 4;
    const float* aSrc0 = X + (size_t)(t0 + ar0) * HIDDEN + ak0;
    const float* aSrc1 = X + (size_t)(t0 + ar1) * HIDDEN + ak1;
    // B: wave w stages slab chunks w*8 .. w*8+7
    const unsigned short* bSrc = Ws + ((size_t)wid * 8) * 512 + (size_t)lane * 8;

    // compute geometry (A swizzled read)
    const int cr = lane & 31;
    const int kb = (lane >> 5) * 2;
    int aoff[4][2];
#pragma unroll
    for (int s = 0; s < 4; ++s) {
        aoff[s][0] = cr * 64 + (((s * 4 + kb + 0) ^ (cr & 15)) * 4);
        aoff[s][1] = cr * 64 + (((s * 4 + kb + 1) ^ (cr & 15)) * 4);
    }
    const int boff = (wid * 2) * 512 + lane * 8;

    f32x16 acc;
#pragma unroll
    for (int r = 0; r < 16; ++r) acc[r] = 0.f;

    // ---- prologue: stage iter 0 -> buf0, iter 1 -> buf1 (20 DMAs in flight)
#pragma unroll
    for (int kt = 0; kt < 2; ++kt) {
        load_lds_16B(aSrc0 + kt * BK, &sA[kt][ai0 * 256]);
        load_lds_16B(aSrc1 + kt * BK, &sA[kt][ai1 * 256]);
#pragma unroll
        for (int i = 0; i < 8; ++i)
            load_lds_16B(bSrc + ((size_t)kt * 32 + i) * 512, &sB[kt][(wid * 8 + i) * 512]);
    }
    asm volatile("s_waitcnt vmcnt(10)" ::: "memory");   // iter 0 landed
    __builtin_amdgcn_s_barrier();
    asm volatile("" ::: "memory");

#pragma unroll 1
    for (int kt = 0; kt < KIT; ++kt) {
        const int cur = kt & 1;
        const float* aBuf = &sA[cur][0];
        const unsigned short* bBuf = &sB[cur][0];

        // ---- compute current buffer: 4 k16-steps x 3 split-terms ----
#pragma unroll
        for (int s = 0; s < 4; ++s) {
            const float4 f0 = *(const float4*)(aBuf + aoff[s][0]);
            const float4 f1 = *(const float4*)(aBuf + aoff[s][1]);
            const bf16x8 ah = pack8_hi(f0, f1);
            const bf16x8 al = pack8_lo(f0, f1);
            const bf16x8 bh = *(const bf16x8*)(bBuf + boff + s * 4096);
            const bf16x8 bl = *(const bf16x8*)(bBuf + boff + s * 4096 + 512);
            acc = __builtin_amdgcn_mfma_f32_32x32x16_bf16(ah, bh, acc, 0, 0, 0);
            acc = __builtin_amdgcn_mfma_f32_32x32x16_bf16(ah, bl, acc, 0, 0, 0);
            acc = __builtin_amdgcn_mfma_f32_32x32x16_bf16(al, bh, acc, 0, 0, 0);
        }

        __builtin_amdgcn_s_barrier();      // all waves done READING buf[cur]
        asm volatile("" ::: "memory");

        // ---- stage iter kt+2 into buf[cur] (clamped tail: redundant, in-bounds)
        int kn = kt + 2; if (kn > KIT - 1) kn = KIT - 1;
        load_lds_16B(aSrc0 + kn * BK, &sA[cur][ai0 * 256]);
        load_lds_16B(aSrc1 + kn * BK, &sA[cur][ai1 * 256]);
#pragma unroll
        for (int i = 0; i < 8; ++i)
            load_lds_16B(bSrc + ((size_t)kn * 32 + i) * 512, &sB[cur][(wid * 8 + i) * 512]);

        // counted wait: iter kt+1's 10 DMAs landed; the 10 just issued remain
        // in flight across the barrier (never drain to 0 in the loop).
        asm volatile("s_waitcnt vmcnt(10)" ::: "memory");
        __builtin_amdgcn_sched_barrier(0);
        __builtin_amdgcn_s_barrier();      // all waves' next-iter data visible
        asm volatile("" ::: "memory");
    }
    asm volatile("s_waitcnt vmcnt(0)" ::: "memory");    // own DMAs drained
    __builtin_amdgcn_s_barrier();                       // everyone drained -> sA dead
    asm volatile("" ::: "memory");

    // ---- epilogue 1: write logits to global AND stage the 32x128 tile in LDS
    // C/D: col=lane&31, row=(reg&3)+8*(reg>>2)+4*(lane>>5)  (r6-verified)
    const int e = wid * 32 + (lane & 31);
    const int rbase = 4 * (lane >> 5);
#pragma unroll
    for (int reg = 0; reg < 16; ++reg) {
        const int row = (reg & 3) + 8 * (reg >> 2) + rbase;
        logits[(size_t)(t0 + row) * NEXP + e] = acc[reg];
        sLog[row * NEXP + e] = acc[reg];   // lanes 0..31 -> 32 distinct banks
    }
    __builtin_amdgcn_s_barrier();          // tile complete
    asm volatile("" ::: "memory");

    // ---- epilogue 2: fused select+refine, wave-per-token, 8 tokens/wave ----
#pragma unroll 1
    for (int tk = 0; tk < 8; ++tk) {
        const int trow = wid * 8 + tk;
        const size_t t = (size_t)t0 + trow;
        const float l0 = sLog[trow * NEXP + lane];
        const float l1 = sLog[trow * NEXP + lane + 64];
        bool r0 = false, r1 = false;
        float vals[NCAND]; int idxs[NCAND];

#pragma unroll
        for (int it = 0; it < TOPK + 1; ++it) {
            const float c0 = r0 ? -FLT_MAX : l0;
            const float c1 = r1 ? -FLT_MAX : l1;
            float v; int id;
            if (c1 > c0) { v = c1; id = lane + 64; }
            else         { v = c0; id = lane; }
#pragma unroll
            for (int off = 1; off < 64; off <<= 1) {
                const float ov = __shfl_xor(v, off);
                const int   oi = __shfl_xor(id, off);
                if (ov > v || (ov == v && oi < id)) { v = ov; id = oi; }
            }
            vals[it] = v; idxs[it] = id;
            if (id == lane) r0 = true;
            else if (id == lane + 64) r1 = true;
        }

        float ming = FLT_MAX;
#pragma unroll
        for (int i = 0; i < TOPK; ++i) ming = fminf(ming, vals[i] - vals[i + 1]);

        if (ming >= DELTA) {
            if (lane == 0) {
                const float m = vals[0];
                float ex[TOPK], s = 0.f;
#pragma unroll
                for (int i = 0; i < TOPK; ++i) { ex[i] = expf(vals[i] - m); s += ex[i]; }
                const float inv = 1.f / s;
#pragma unroll
                for (int i = 0; i < TOPK; ++i) {
                    top_vals[t * TOPK + i] = ex[i] * inv;
                    top_idx[t * TOPK + i] = (float)idxs[i];
                }
            }
            continue;
        }

        // ---- slow path (wave-uniform): extend candidates to NCAND
#pragma unroll
        for (int it = TOPK + 1; it < NCAND; ++it) {
            const float c0 = r0 ? -FLT_MAX : l0;
            const float c1 = r1 ? -FLT_MAX : l1;
            float v; int id;
            if (c1 > c0) { v = c1; id = lane + 64; }
            else         { v = c0; id = lane; }
#pragma unroll
            for (int off = 1; off < 64; off <<= 1) {
                const float ov = __shfl_xor(v, off);
                const int   oi = __shfl_xor(id, off);
                if (ov > v || (ov == v && oi < id)) { v = ov; id = oi; }
            }
            vals[it] = v; idxs[it] = id;
            if (id == lane) r0 = true;
            else if (id == lane + 64) r1 = true;
        }

        // exact fp64 recompute of the NCAND candidate logits (coalesced)
        const float* xr = X + t * HIDDEN;
        double xd[32];
#pragma unroll
        for (int j = 0; j < 8; ++j) {
            const float4 v = *(const float4*)(xr + j * 256 + lane * 4);
            xd[j * 4 + 0] = (double)v.x; xd[j * 4 + 1] = (double)v.y;
            xd[j * 4 + 2] = (double)v.z; xd[j * 4 + 3] = (double)v.w;
        }
        double accد[NCAND];
#pragma unroll
        for (int c = 0; c < NCAND; ++c) {
            const float* wr = W + (size_t)idxs[c] * HIDDEN;
            double a0 = 0.0, a1 = 0.0;
#pragma unroll
            for (int j = 0; j < 8; ++j) {
                const float4 w = *(const float4*)(wr + j * 256 + lane * 4);
                a0 = fma((double)w.x, xd[j * 4 + 0], a0);
                a1 = fma((double)w.y, xd[j * 4 + 1], a1);
                a0 = fma((double)w.z, xd[j * 4 + 2], a0);
                a1 = fma((double)w.w, xd[j * 4 + 3], a1);
            }
            accد[c] = a0 + a1;
        }
#pragma unroll
        for (int c = 0; c < NCAND; ++c)
#pragma unroll
            for (int off = 1; off < 64; off <<= 1)
                accد[c] += __shfl_xor(accد[c], off);

        int rank[NCAND];
#pragma unroll
        for (int c = 0; c < NCAND; ++c) {
            int r = 0;
#pragma unroll
            for (int m = 0; m < NCAND; ++m)
                if (accد[m] > accد[c] || (accد[m] == accد[c] && idxs[m] < idxs[c])) ++r;
            rank[c] = r;
        }
        double vmax = accد[0];
#pragma unroll
        for (int c = 0; c < NCAND; ++c) if (rank[c] == 0) vmax = accد[c];
        float ex[NCAND], s = 0.f;
#pragma unroll
        for (int c = 0; c < NCAND; ++c) {
            ex[c] = (rank[c] < TOPK) ? expf((float)(accد[c] - vmax)) : 0.f;
            s += ex[c];
        }
        const float inv = 1.f / s;
        if (lane == 0) {
#pragma unroll
            for (int c = 0; c < NCAND; ++c)
                if (rank[c] < TOPK) {
                    top_vals[t * TOPK + rank[c]] = ex[c] * inv;
                    top_idx[t * TOPK + rank[c]] = (float)idxs[c];
                }
        }
    }
}

extern "C" void kernel_launch(void* const* d_in, const int* in_sizes, int n_in,
                              void* d_out, int out_size, void* d_ws, size_t ws_size,
                              hipStream_t stream) {
    const float* X = (const float*)d_in[0];   // [16384, 2048] f32
    const float* W = (const float*)d_in[1];   // [128, 2048] f32
    float* logits = (float*)d_out;                          // [16384,128]
    float* tvals  = logits + (size_t)TOKENS * NEXP;         // [16384,8]
    float* tidx   = tvals + (size_t)TOKENS * TOPK;          // [16384,8]

    unsigned short* Wsplit = (unsigned short*)d_ws;         // 1 MB

    presplit_w<<<256, 256, 0, stream>>>(W, Wsplit);
    router_gemm<<<TOKENS / BM, 256, 0, stream>>>(X, Wsplit, W, logits, tvals, tidx);
}